// Round 1
// baseline (1009.658 us; speedup 1.0000x reference)
//
#include <hip/hip_runtime.h>

// Problem constants (reference: B=2048, E=32, N=32, D=64)
#define B_  2048
#define E_  32
#define N_  32
#define D_  64

// One block per (b,e) pair. 256 threads.
// Tile = N*D = 2048 floats = 512 float4. Thread t handles float4 j=t and j=t+256.
//   j -> n = j>>4, d4 = j&15   (D=64 floats = 16 float4 per neighbor row)
__global__ __launch_bounds__(256) void kgcn_kernel(
    const float* __restrict__ self_v,   // [B,E,D]
    const float* __restrict__ nv,       // [B,E,N,D]
    const float* __restrict__ rel,      // [B,E,N,D]
    const float* __restrict__ user,     // [B,D]
    const float* __restrict__ W,        // [D,D]
    const float* __restrict__ blin,     // [D]
    float* __restrict__ out)            // [B,E,D]
{
    const int be = blockIdx.x;          // 0 .. B*E-1
    const int b  = be >> 5;             // E = 32
    const int t  = threadIdx.x;
    const int n0 = t >> 4;              // 0..15
    const int d4 = t & 15;              // 0..15

    __shared__ float  s_score[N_];      // raw scores, then reused
    __shared__ float  s_attn[N_];       // softmax(scores)/N
    __shared__ float4 s_acc[256];       // weighted-sum partials
    __shared__ float4 s_pre[D_ / 4];    // self + agg (pre-linear)

    const float4* rel4 = (const float4*)rel + (size_t)be * 512;
    const float4* nv4  = (const float4*)nv  + (size_t)be * 512;

    // ---- issue all global loads up front (latency hiding) ----
    float4 r0 = rel4[t];
    float4 r1 = rel4[t + 256];
    float4 v0 = nv4[t];
    float4 v1 = nv4[t + 256];
    float4 u4 = ((const float4*)user)[b * 16 + d4];

    // ---- phase 1: scores[n] = (user . rel[n]) / D ----
    float p0 = r0.x * u4.x + r0.y * u4.y + r0.z * u4.z + r0.w * u4.w; // n = n0
    float p1 = r1.x * u4.x + r1.y * u4.y + r1.z * u4.z + r1.w * u4.w; // n = n0+16

    // butterfly reduce across the 16 lanes sharing one n (lanes grouped by d4)
    #pragma unroll
    for (int m = 1; m < 16; m <<= 1) {
        p0 += __shfl_xor(p0, m);
        p1 += __shfl_xor(p1, m);
    }
    if (d4 == 0) {
        s_score[n0]      = p0 * (1.0f / (float)D_);
        s_score[n0 + 16] = p1 * (1.0f / (float)D_);
    }
    __syncthreads();

    // ---- softmax over n (32 values), fold 1/N mean into attn ----
    if (t < N_) {
        float m = -1e30f;
        #pragma unroll
        for (int n = 0; n < N_; ++n) m = fmaxf(m, s_score[n]);   // broadcast reads
        float e = __expf(s_score[t] - m);
        s_attn[t] = e;   // temp: exp
    }
    __syncthreads();
    if (t < N_) {
        float s = 0.0f;
        #pragma unroll
        for (int n = 0; n < N_; ++n) s += s_attn[n];             // broadcast reads
        s_score[t] = s_attn[t] / (s * (float)N_);                // attn/N, final
    }
    __syncthreads();

    // ---- phase 2: agg[d] = sum_n attn[n] * nv[n,d] ----
    {
        const float a0 = s_score[n0];
        const float a1 = s_score[n0 + 16];
        float4 acc;
        acc.x = a0 * v0.x + a1 * v1.x;
        acc.y = a0 * v0.y + a1 * v1.y;
        acc.z = a0 * v0.z + a1 * v1.z;
        acc.w = a0 * v0.w + a1 * v1.w;
        s_acc[t] = acc;   // index t = n0*16 + d4
    }
    __syncthreads();

    // reduce the 16 partials per d4 (stride-16 float4 = 2-way bank alias = free),
    // add self, stash pre-linear vector
    if (t < 16) {
        float4 s = s_acc[t];
        #pragma unroll
        for (int k = 1; k < 16; ++k) {
            float4 x = s_acc[t + 16 * k];
            s.x += x.x; s.y += x.y; s.z += x.z; s.w += x.w;
        }
        float4 sv = ((const float4*)self_v)[(size_t)be * 16 + t];
        s.x += sv.x; s.y += sv.y; s.z += sv.z; s.w += sv.w;
        s_pre[t] = s;
    }
    __syncthreads();

    // ---- phase 3: out[d] = relu( sum_k pre[k]*W[d,k] + b[d] ), one thread per d ----
    if (t < D_) {
        float acc = blin[t];
        const float4* Wrow = (const float4*)W + t * 16;   // row-major W[d][k]
        #pragma unroll
        for (int k4 = 0; k4 < 16; ++k4) {
            float4 w = Wrow[k4];
            float4 p = s_pre[k4];
            acc += w.x * p.x + w.y * p.y + w.z * p.z + w.w * p.w;
        }
        out[(size_t)be * 64 + t] = fmaxf(acc, 0.0f);
    }
}

extern "C" void kernel_launch(void* const* d_in, const int* in_sizes, int n_in,
                              void* d_out, int out_size, void* d_ws, size_t ws_size,
                              hipStream_t stream) {
    const float* self_v = (const float*)d_in[0];   // [B,E,D]
    const float* nv     = (const float*)d_in[1];   // [B,E,N,D]
    const float* rel    = (const float*)d_in[2];   // [B,E,N,D]
    const float* user   = (const float*)d_in[3];   // [B,D]
    // d_in[4] = masks (unused by the module)
    const float* W      = (const float*)d_in[5];   // [D,D]
    const float* blin   = (const float*)d_in[6];   // [D]
    float* out          = (float*)d_out;           // [B,E,D]

    const int blocks = B_ * E_;                    // 65536
    kgcn_kernel<<<blocks, 256, 0, stream>>>(self_v, nv, rel, user, W, blin, out);
}